// Round 1
// baseline (273.535 us; speedup 1.0000x reference)
//
#include <hip/hip_runtime.h>
#include <hip/hip_bf16.h>
#include <stdint.h>

typedef __attribute__((ext_vector_type(8))) short bf16x8;
typedef __attribute__((ext_vector_type(4))) float f32x4;

#define LQ 2048
#define CDIM 1024
#define NHEAD 16
#define HD 64

__device__ __forceinline__ short f2bf(float f) {
  union { float f; uint32_t u; } v; v.f = f;
  uint32_t r = v.u + 0x7fffu + ((v.u >> 16) & 1u);
  return (short)(r >> 16);
}

// XOR swizzle for [rows][64] bf16 (short) LDS arrays: spreads the 16B chunks of
// 8 consecutive rows across all 32 banks (G4: row-major stride-128B = 16-way conflict).
__device__ __forceinline__ int swz(int row, int col) {
  return (row << 6) + (col ^ ((row & 7) << 3));
}

__device__ __forceinline__ bf16x8 pack8(f32x4 a, f32x4 b) {
  bf16x8 r;
  r[0] = f2bf(a[0]); r[1] = f2bf(a[1]); r[2] = f2bf(a[2]); r[3] = f2bf(a[3]);
  r[4] = f2bf(b[0]); r[5] = f2bf(b[1]); r[6] = f2bf(b[2]); r[7] = f2bf(b[3]);
  return r;
}

// C[m][n] = sum_k A[m][k] * B[n][k]   (both operands row-major, NT layout)
// 128x128 tile, BK=64, 4 waves each owning a 64x64 quadrant (4x4 fragments).
template<bool A_BF16, bool OUT_BF16>
__device__ __forceinline__ void gemm_tile(const void* Ap, const float* __restrict__ B,
                                          void* Cp, int m0, int n0, int K, int ldc)
{
  __shared__ alignas(16) short Alds[128 * 64];
  __shared__ alignas(16) short Blds[128 * 64];

  const int t = threadIdx.x;
  const int lane = t & 63;
  const int wid = t >> 6;
  const int wr = (wid >> 1) * 64;
  const int wc = (wid & 1) * 64;
  const int l15 = lane & 15;
  const int l4 = lane >> 4;

  f32x4 acc[4][4];
#pragma unroll
  for (int i = 0; i < 4; ++i)
#pragma unroll
    for (int j = 0; j < 4; ++j)
      acc[i][j] = f32x4{0.f, 0.f, 0.f, 0.f};

  const int srow = t >> 1;          // 0..127 staging row
  const int scol = (t & 1) * 32;    // half-row

  for (int k0 = 0; k0 < K; k0 += 64) {
    __syncthreads();
    // ---- stage A tile (128 x 64) ----
    if (A_BF16) {
      const short* ag = (const short*)Ap + (size_t)(m0 + srow) * K + k0 + scol;
#pragma unroll
      for (int c = 0; c < 4; ++c) {
        bf16x8 v = *(const bf16x8*)(ag + c * 8);
        *(bf16x8*)&Alds[swz(srow, scol + c * 8)] = v;
      }
    } else {
      const float* ag = (const float*)Ap + (size_t)(m0 + srow) * K + k0 + scol;
#pragma unroll
      for (int c = 0; c < 4; ++c) {
        f32x4 x0 = *(const f32x4*)(ag + c * 8);
        f32x4 x1 = *(const f32x4*)(ag + c * 8 + 4);
        *(bf16x8*)&Alds[swz(srow, scol + c * 8)] = pack8(x0, x1);
      }
    }
    // ---- stage B tile (128 x 64), always fp32 W ----
    {
      const float* bg = B + (size_t)(n0 + srow) * K + k0 + scol;
#pragma unroll
      for (int c = 0; c < 4; ++c) {
        f32x4 x0 = *(const f32x4*)(bg + c * 8);
        f32x4 x1 = *(const f32x4*)(bg + c * 8 + 4);
        *(bf16x8*)&Blds[swz(srow, scol + c * 8)] = pack8(x0, x1);
      }
    }
    __syncthreads();
    // ---- MFMA inner loop ----
#pragma unroll
    for (int kh = 0; kh < 2; ++kh) {
      bf16x8 af[4], bfr[4];
#pragma unroll
      for (int i = 0; i < 4; ++i)
        af[i] = *(const bf16x8*)&Alds[swz(wr + i * 16 + l15, kh * 32 + l4 * 8)];
#pragma unroll
      for (int j = 0; j < 4; ++j)
        bfr[j] = *(const bf16x8*)&Blds[swz(wc + j * 16 + l15, kh * 32 + l4 * 8)];
#pragma unroll
      for (int i = 0; i < 4; ++i)
#pragma unroll
        for (int j = 0; j < 4; ++j)
          acc[i][j] = __builtin_amdgcn_mfma_f32_16x16x32_bf16(af[i], bfr[j], acc[i][j], 0, 0, 0);
    }
  }
  // ---- epilogue: C/D layout col=lane&15, row=(lane>>4)*4+reg ----
#pragma unroll
  for (int i = 0; i < 4; ++i)
#pragma unroll
    for (int j = 0; j < 4; ++j)
#pragma unroll
      for (int r = 0; r < 4; ++r) {
        int rr = m0 + wr + i * 16 + l4 * 4 + r;
        int cc = n0 + wc + j * 16 + l15;
        if (OUT_BF16)
          ((short*)Cp)[(size_t)rr * ldc + cc] = f2bf(acc[i][j][r]);
        else
          ((float*)Cp)[(size_t)rr * ldc + cc] = acc[i][j][r];
      }
}

// Fused Q/K/V projection: grid (M/128=32, 3*N/128=24). n-block selects tensor.
__global__ __launch_bounds__(256) void proj_kernel(const float* __restrict__ q, const float* __restrict__ k,
                                                   const float* __restrict__ v,
                                                   const float* __restrict__ Wq, const float* __restrict__ Wk,
                                                   const float* __restrict__ Wv,
                                                   short* __restrict__ qp, short* __restrict__ kp,
                                                   short* __restrict__ vp)
{
  int nb = blockIdx.y;
  int sel = nb >> 3;
  int n0 = (nb & 7) * 128;
  int m0 = blockIdx.x * 128;
  const float* A = sel == 0 ? q : (sel == 1 ? k : v);
  const float* B = sel == 0 ? Wq : (sel == 1 ? Wk : Wv);
  short* C = sel == 0 ? qp : (sel == 1 ? kp : vp);
  gemm_tile<false, true>(A, B, C, m0, n0, CDIM, CDIM);
}

__global__ __launch_bounds__(256) void out_kernel(const short* __restrict__ at, const float* __restrict__ Wo,
                                                  float* __restrict__ out)
{
  gemm_tile<true, false>(at, Wo, out, blockIdx.x * 128, blockIdx.y * 128, CDIM, CDIM);
}

// Flash attention: one block per (b,h,q-tile of 64 rows). 4 waves x 16 q-rows.
// grid.x = b*h (32, fastest -> spreads heads over XCDs, K/V stays L2-hot),
// grid.y = q-tile (32).
__global__ __launch_bounds__(256) void attn_kernel(const short* __restrict__ qp, const short* __restrict__ kp,
                                                   const short* __restrict__ vp, short* __restrict__ attn)
{
  __shared__ alignas(16) short Klds[64 * 64];   // [kk][d], swizzled
  __shared__ alignas(16) short Vt[64 * 64];     // [d][kk], swizzled (transposed on stage)
  __shared__ alignas(16) short Plds[64 * 64];   // [q_local][kk], swizzled, wave-private 16-row slices

  const int bh = blockIdx.x;
  const int b = bh >> 4;
  const int h = bh & 15;
  const int q0 = blockIdx.y * 64;
  const int t = threadIdx.x;
  const int lane = t & 63;
  const int wid = t >> 6;
  const int l15 = lane & 15;
  const int l4 = lane >> 4;

  const size_t base = (size_t)b * LQ * CDIM + (size_t)h * HD;

  // Q A-fragments held in registers for the whole block (16 rows per wave, K=64 -> 2 frags)
  bf16x8 aq[2];
#pragma unroll
  for (int kh = 0; kh < 2; ++kh)
    aq[kh] = *(const bf16x8*)(qp + base + (size_t)(q0 + wid * 16 + l15) * CDIM + kh * 32 + l4 * 8);

  f32x4 oacc[4];
#pragma unroll
  for (int fn = 0; fn < 4; ++fn) oacc[fn] = f32x4{0.f, 0.f, 0.f, 0.f};
  float mrun[4] = {-1e30f, -1e30f, -1e30f, -1e30f};
  float lrun[4] = {0.f, 0.f, 0.f, 0.f};

  const int krow = t >> 2;          // K staging: row kk = t>>2, 16 bf16 per thread
  const int kcol = (t & 3) << 4;
  const int vkk = lane;             // V staging: one kk column per lane -> conflict-free Vt writes
  const int vd0 = wid * 16;

  for (int kt = 0; kt < LQ / 64; ++kt) {
    __syncthreads();
    // ---- stage K tile [64][64] and V tile transposed [d][kk] ----
    {
      const short* kg = kp + base + (size_t)(kt * 64 + krow) * CDIM + kcol;
      bf16x8 kv0 = *(const bf16x8*)kg;
      bf16x8 kv1 = *(const bf16x8*)(kg + 8);
      *(bf16x8*)&Klds[swz(krow, kcol)] = kv0;
      *(bf16x8*)&Klds[swz(krow, kcol + 8)] = kv1;

      const short* vg = vp + base + (size_t)(kt * 64 + vkk) * CDIM + vd0;
      bf16x8 vv0 = *(const bf16x8*)vg;
      bf16x8 vv1 = *(const bf16x8*)(vg + 8);
#pragma unroll
      for (int j = 0; j < 8; ++j) Vt[swz(vd0 + j, vkk)] = vv0[j];
#pragma unroll
      for (int j = 0; j < 8; ++j) Vt[swz(vd0 + 8 + j, vkk)] = vv1[j];
    }
    __syncthreads();

    // ---- S = Q K^T (per wave: 16 q-rows x 64 kk) ----
    f32x4 s[4];
#pragma unroll
    for (int fn = 0; fn < 4; ++fn) s[fn] = f32x4{0.f, 0.f, 0.f, 0.f};
#pragma unroll
    for (int kh = 0; kh < 2; ++kh) {
#pragma unroll
      for (int fn = 0; fn < 4; ++fn) {
        bf16x8 bk = *(const bf16x8*)&Klds[swz(fn * 16 + l15, kh * 32 + l4 * 8)];
        s[fn] = __builtin_amdgcn_mfma_f32_16x16x32_bf16(aq[kh], bk, s[fn], 0, 0, 0);
      }
    }

    // ---- online softmax (fp32). Row r lives in the 16 lanes sharing l4; reduce via shfl_xor. ----
    float corr[4];
#pragma unroll
    for (int r = 0; r < 4; ++r) {
      float m = fmaxf(fmaxf(s[0][r], s[1][r]), fmaxf(s[2][r], s[3][r]));
#pragma unroll
      for (int d = 1; d < 16; d <<= 1) m = fmaxf(m, __shfl_xor(m, d, 64));
      m *= 0.125f;  // 1/sqrt(64)
      float mn = fmaxf(mrun[r], m);
      corr[r] = __expf(mrun[r] - mn);
      mrun[r] = mn;
    }
    float psum[4] = {0.f, 0.f, 0.f, 0.f};
#pragma unroll
    for (int fn = 0; fn < 4; ++fn)
#pragma unroll
      for (int r = 0; r < 4; ++r) {
        float p = __expf(s[fn][r] * 0.125f - mrun[r]);
        psum[r] += p;
        Plds[swz(wid * 16 + l4 * 4 + r, fn * 16 + l15)] = f2bf(p);
      }
#pragma unroll
    for (int r = 0; r < 4; ++r) {
      float su = psum[r];
#pragma unroll
      for (int d = 1; d < 16; d <<= 1) su += __shfl_xor(su, d, 64);
      lrun[r] = lrun[r] * corr[r] + su;
    }
#pragma unroll
    for (int fn = 0; fn < 4; ++fn)
#pragma unroll
      for (int r = 0; r < 4; ++r) oacc[fn][r] *= corr[r];

    // P slice is wave-private; wave-internal ds_write -> ds_read needs completion wait only.
    asm volatile("s_waitcnt lgkmcnt(0)" ::: "memory");

    // ---- O += P V ----
#pragma unroll
    for (int kh = 0; kh < 2; ++kh) {
      bf16x8 ap = *(const bf16x8*)&Plds[swz(wid * 16 + l15, kh * 32 + l4 * 8)];
#pragma unroll
      for (int fn = 0; fn < 4; ++fn) {
        bf16x8 bv = *(const bf16x8*)&Vt[swz(fn * 16 + l15, kh * 32 + l4 * 8)];
        oacc[fn] = __builtin_amdgcn_mfma_f32_16x16x32_bf16(ap, bv, oacc[fn], 0, 0, 0);
      }
    }
  }

  // ---- finalize: O / l, write bf16 ----
#pragma unroll
  for (int fn = 0; fn < 4; ++fn)
#pragma unroll
    for (int r = 0; r < 4; ++r) {
      size_t idx = base + (size_t)(q0 + wid * 16 + l4 * 4 + r) * CDIM + fn * 16 + l15;
      attn[idx] = f2bf(oacc[fn][r] / lrun[r]);
    }
}

extern "C" void kernel_launch(void* const* d_in, const int* in_sizes, int n_in,
                              void* d_out, int out_size, void* d_ws, size_t ws_size,
                              hipStream_t stream) {
  const float* q  = (const float*)d_in[0];
  const float* k  = (const float*)d_in[1];
  const float* v  = (const float*)d_in[2];
  const float* Wq = (const float*)d_in[3];
  const float* Wk = (const float*)d_in[4];
  const float* Wv = (const float*)d_in[5];
  const float* Wo = (const float*)d_in[6];
  float* out = (float*)d_out;

  const size_t NTOK = (size_t)2 * LQ;          // 4096 rows
  short* qp = (short*)d_ws;                    // [4096][1024] bf16
  short* kp = qp + NTOK * CDIM;
  short* vp = kp + NTOK * CDIM;
  short* at = vp + NTOK * CDIM;                // attention output, bf16
  // total ws use: 4 * 8 MB = 32 MB

  proj_kernel<<<dim3(32, 24), 256, 0, stream>>>(q, k, v, Wq, Wk, Wv, qp, kp, vp);
  attn_kernel<<<dim3(32, 32), 256, 0, stream>>>(qp, kp, vp, at);
  out_kernel<<<dim3(32, 8), 256, 0, stream>>>(at, Wo, out);
}

// Round 3
// 205.124 us; speedup vs baseline: 1.3335x; 1.3335x over previous
//
#include <hip/hip_runtime.h>
#include <hip/hip_bf16.h>
#include <stdint.h>

typedef __attribute__((ext_vector_type(8))) short bf16x8;
typedef __attribute__((ext_vector_type(4))) float f32x4;
typedef __attribute__((ext_vector_type(4))) uint32_t u32x4;

#define LQ 2048
#define CDIM 1024
#define NTOK 4096
#define WELEM 1048576

__device__ __forceinline__ short f2bf(float f) {
  union { float f; uint32_t u; } v; v.f = f;
  uint32_t r = v.u + 0x7fffu + ((v.u >> 16) & 1u);
  return (short)(r >> 16);
}

__device__ __forceinline__ uint32_t cvt_pk_bf16(float a, float b) {
  uint32_t r;
  asm("v_cvt_pk_bf16_f32 %0, %1, %2" : "=v"(r) : "v"(a), "v"(b));
  return r;
}

// XOR swizzle for [rows][64] bf16 LDS tiles
__device__ __forceinline__ int swz(int row, int col) {
  return (row << 6) + (col ^ ((row & 7) << 3));
}

// global -> LDS direct copy, 16B per lane. LDS dest = wave-uniform base + lane*16.
// Proper addrspacecast pointers (NOT a truncated generic pointer).
__device__ __forceinline__ void gl_lds16(const void* g, void* lds) {
  __builtin_amdgcn_global_load_lds(
      (const __attribute__((address_space(1))) void*)g,
      (__attribute__((address_space(3))) void*)lds, 16, 0, 0);
}

// ---------------- weight fp32 -> bf16 convert ----------------
__global__ __launch_bounds__(256) void convw_kernel(const float* __restrict__ wq, const float* __restrict__ wk,
                                                    const float* __restrict__ wv, const float* __restrict__ wo,
                                                    short* __restrict__ dst) {
  const int NG = (4 * WELEM) / 8;
  for (int i = blockIdx.x * 256 + threadIdx.x; i < NG; i += gridDim.x * 256) {
    int e = i * 8;
    int seg = e >> 20;
    int off = e & (WELEM - 1);
    const float* s = seg == 0 ? wq : seg == 1 ? wk : seg == 2 ? wv : wo;
    f32x4 x0 = *(const f32x4*)(s + off);
    f32x4 x1 = *(const f32x4*)(s + off + 4);
    u32x4 r = { cvt_pk_bf16(x0[0], x0[1]), cvt_pk_bf16(x0[2], x0[3]),
                cvt_pk_bf16(x1[0], x1[1]), cvt_pk_bf16(x1[2], x1[3]) };
    *(u32x4*)(dst + e) = r;
  }
}

// ---------------- GEMM core: C[m][n] = sum_k A[m][k] B[n][k] ----------------
// A tile 128 x 64; B tile BN x 64; BK=64. B staged via global_load_lds (bf16 src, linear LDS).
// A either fp32 reg-staged + cvt_pk (swizzled LDS) or bf16 via global_load_lds (linear LDS).
template<bool A_BF16, bool OUT_BF16, int BN>
__device__ __forceinline__ void gemm_core(const void* Ap, const short* __restrict__ Bp,
                                          void* Cp, int m0, int n0, int K, int ldc)
{
  __shared__ alignas(16) short Alds[128 * 64];
  __shared__ alignas(16) short Blds[BN * 64];

  const int t = threadIdx.x;
  const int lane = t & 63;
  const int wid = t >> 6;
  const int l15 = lane & 15, l4 = lane >> 4;
  constexpr int NI = (BN == 128) ? 4 : 2;          // row frags per wave
  const int wr = (BN == 128) ? (wid >> 1) * 64 : wid * 32;
  const int wc = (BN == 128) ? (wid & 1) * 64 : 0;

  f32x4 acc[NI][4];
#pragma unroll
  for (int i = 0; i < NI; ++i)
#pragma unroll
    for (int j = 0; j < 4; ++j) acc[i][j] = f32x4{0.f, 0.f, 0.f, 0.f};

  const int grow = lane >> 3;            // 0..7
  const int gcol = (lane & 7) * 8;       // bf16 elems
  constexpr int BI = BN / 32;            // B gl_lds instrs per wave
  const short* bsrc = Bp + (size_t)(n0 + wid * (BN / 4) + grow) * K + gcol;
  const short* asrcb = (const short*)Ap + (size_t)(m0 + wid * 32 + grow) * K + gcol;
  const int srow = t >> 1, scol = (t & 1) * 32;
  const float* asrcf = (const float*)Ap + (size_t)(m0 + srow) * K + scol;

  for (int k0 = 0; k0 < K; k0 += 64) {
    __syncthreads();
#pragma unroll
    for (int c = 0; c < BI; ++c)
      gl_lds16(bsrc + (size_t)c * 8 * K + k0, &Blds[(wid * BI + c) * 512]);
    if (A_BF16) {
#pragma unroll
      for (int c = 0; c < 4; ++c)
        gl_lds16(asrcb + (size_t)c * 8 * K + k0, &Alds[(wid * 4 + c) * 512]);
    } else {
      const float* ag = asrcf + k0;
#pragma unroll
      for (int cc = 0; cc < 4; ++cc) {
        f32x4 x0 = *(const f32x4*)(ag + cc * 8);
        f32x4 x1 = *(const f32x4*)(ag + cc * 8 + 4);
        u32x4 r = { cvt_pk_bf16(x0[0], x0[1]), cvt_pk_bf16(x0[2], x0[3]),
                    cvt_pk_bf16(x1[0], x1[1]), cvt_pk_bf16(x1[2], x1[3]) };
        *(u32x4*)&Alds[swz(srow, scol + cc * 8)] = r;
      }
    }
    __syncthreads();
#pragma unroll
    for (int kh = 0; kh < 2; ++kh) {
      bf16x8 af[NI], bfr[4];
#pragma unroll
      for (int i = 0; i < NI; ++i) {
        int row = wr + i * 16 + l15;
        af[i] = A_BF16 ? *(const bf16x8*)&Alds[row * 64 + kh * 32 + l4 * 8]
                       : *(const bf16x8*)&Alds[swz(row, kh * 32 + l4 * 8)];
      }
#pragma unroll
      for (int j = 0; j < 4; ++j)
        bfr[j] = *(const bf16x8*)&Blds[(wc + j * 16 + l15) * 64 + kh * 32 + l4 * 8];
      __builtin_amdgcn_s_setprio(1);
#pragma unroll
      for (int i = 0; i < NI; ++i)
#pragma unroll
        for (int j = 0; j < 4; ++j)
          acc[i][j] = __builtin_amdgcn_mfma_f32_16x16x32_bf16(af[i], bfr[j], acc[i][j], 0, 0, 0);
      __builtin_amdgcn_s_setprio(0);
    }
  }
#pragma unroll
  for (int i = 0; i < NI; ++i)
#pragma unroll
    for (int j = 0; j < 4; ++j)
#pragma unroll
      for (int r = 0; r < 4; ++r) {
        int rr = m0 + wr + i * 16 + l4 * 4 + r;
        int cc = n0 + wc + j * 16 + l15;
        if (OUT_BF16) ((short*)Cp)[(size_t)rr * ldc + cc] = f2bf(acc[i][j][r]);
        else          ((float*)Cp)[(size_t)rr * ldc + cc] = acc[i][j][r];
      }
}

__global__ __launch_bounds__(256) void proj_kernel(const float* __restrict__ q, const float* __restrict__ k,
                                                   const float* __restrict__ v, const short* __restrict__ wbf,
                                                   short* __restrict__ qp, short* __restrict__ kp,
                                                   short* __restrict__ vp)
{
  int nb = blockIdx.y;
  int sel = nb >> 3;
  int n0 = (nb & 7) * 128;
  int m0 = blockIdx.x * 128;
  const float* A = sel == 0 ? q : (sel == 1 ? k : v);
  const short* B = wbf + (size_t)sel * WELEM;
  short* C = sel == 0 ? qp : (sel == 1 ? kp : vp);
  gemm_core<false, true, 128>(A, B, C, m0, n0, CDIM, CDIM);
}

__global__ __launch_bounds__(256) void out_kernel(const short* __restrict__ at, const short* __restrict__ wo,
                                                  float* __restrict__ out)
{
  gemm_core<true, false, 64>(at, wo, out, blockIdx.x * 128, blockIdx.y * 64, CDIM, CDIM);
}

// ---------------- flash attention ----------------
// Block = (b, h, 64 q-rows); 4 waves x 16 q-rows; KVBLK=64; D=64.
// Output written IN-PLACE into qp (disjoint slice per block; Q loaded to regs first).
__global__ __launch_bounds__(256) void attn_kernel(const short* __restrict__ kp, const short* __restrict__ vp,
                                                   short* __restrict__ qp)
{
  __shared__ alignas(16) short Klds[64 * 64];   // [kv][d] swizzled
  __shared__ alignas(16) short Vt[64 * 64];     // [d][kv] swizzled (transposed on stage)
  __shared__ alignas(16) short Plds[64 * 64];   // [q_local][kv] swizzled, wave-private 16-row slices

  const int bh = blockIdx.x;
  const int b = bh >> 4, h = bh & 15;
  const int q0 = blockIdx.y * 64;
  const int t = threadIdx.x, lane = t & 63, wid = t >> 6;
  const int l15 = lane & 15, l4 = lane >> 4;
  const size_t base = (size_t)b * LQ * CDIM + (size_t)h * 64;

  // Q fragments in registers for the whole block
  bf16x8 aq[2];
  {
    const short* qrow = qp + base + (size_t)(q0 + wid * 16 + l15) * CDIM;
    aq[0] = *(const bf16x8*)(qrow + l4 * 8);
    aq[1] = *(const bf16x8*)(qrow + 32 + l4 * 8);
  }

  f32x4 oacc[4];
#pragma unroll
  for (int fn = 0; fn < 4; ++fn) oacc[fn] = f32x4{0.f, 0.f, 0.f, 0.f};
  float mrun2[4] = {-1e30f, -1e30f, -1e30f, -1e30f};   // log2-domain running max
  float lrun[4] = {0.f, 0.f, 0.f, 0.f};                // per-lane partial denominators

  const int krow = t >> 2, kcol = (t & 3) << 4;
  const short* ksrc = kp + base + (size_t)krow * CDIM + kcol;
  const short* vsrc = vp + base + (size_t)lane * CDIM + wid * 16;
  const int vd0 = wid * 16, vkk = lane;

  const float SC2 = 0.18033688011112042f;  // log2(e)/8
  const float THR2 = 11.54f;               // 8 * log2(e)

  for (int kt = 0; kt < LQ / 64; ++kt) {
    __syncthreads();
    {
      bf16x8 k0v = *(const bf16x8*)(ksrc);
      bf16x8 k1v = *(const bf16x8*)(ksrc + 8);
      *(bf16x8*)&Klds[swz(krow, kcol)] = k0v;
      *(bf16x8*)&Klds[swz(krow, kcol + 8)] = k1v;
      bf16x8 v0 = *(const bf16x8*)(vsrc);
      bf16x8 v1 = *(const bf16x8*)(vsrc + 8);
#pragma unroll
      for (int j = 0; j < 8; ++j) Vt[swz(vd0 + j, vkk)] = v0[j];
#pragma unroll
      for (int j = 0; j < 8; ++j) Vt[swz(vd0 + 8 + j, vkk)] = v1[j];
      ksrc += 64 * CDIM; vsrc += 64 * CDIM;
    }
    __syncthreads();

    // ---- S = Q K^T : s[fn][r] = S[q=l4*4+r][kv=fn*16+l15] (raw dot) ----
    f32x4 s[4];
#pragma unroll
    for (int fn = 0; fn < 4; ++fn) s[fn] = f32x4{0.f, 0.f, 0.f, 0.f};
    __builtin_amdgcn_s_setprio(1);
#pragma unroll
    for (int kh = 0; kh < 2; ++kh)
#pragma unroll
      for (int fn = 0; fn < 4; ++fn) {
        bf16x8 bk = *(const bf16x8*)&Klds[swz(fn * 16 + l15, kh * 32 + l4 * 8)];
        s[fn] = __builtin_amdgcn_mfma_f32_16x16x32_bf16(aq[kh], bk, s[fn], 0, 0, 0);
      }
    __builtin_amdgcn_s_setprio(0);

    // ---- online softmax, exp2 domain, defer-max ----
    float mx[4];
#pragma unroll
    for (int r = 0; r < 4; ++r) {
      float m = fmaxf(fmaxf(s[0][r], s[1][r]), fmaxf(s[2][r], s[3][r]));
#pragma unroll
      for (int d = 1; d < 16; d <<= 1) m = fmaxf(m, __shfl_xor(m, d, 64));
      mx[r] = m * SC2;
    }
    bool need = (mx[0] > mrun2[0] + THR2) || (mx[1] > mrun2[1] + THR2) ||
                (mx[2] > mrun2[2] + THR2) || (mx[3] > mrun2[3] + THR2);
    if (__any(need)) {
#pragma unroll
      for (int r = 0; r < 4; ++r) {
        float mn = fmaxf(mrun2[r], mx[r]);
        float c = exp2f(mrun2[r] - mn);
        mrun2[r] = mn;
        lrun[r] *= c;
#pragma unroll
        for (int fn = 0; fn < 4; ++fn) oacc[fn][r] *= c;
      }
    }
    float p[4][4];
#pragma unroll
    for (int fn = 0; fn < 4; ++fn)
#pragma unroll
      for (int r = 0; r < 4; ++r) p[fn][r] = exp2f(s[fn][r] * SC2 - mrun2[r]);
#pragma unroll
    for (int r = 0; r < 4; ++r) lrun[r] += p[0][r] + p[1][r] + p[2][r] + p[3][r];

    // ---- P -> wave-private swizzled LDS (round-1-proven path) ----
#pragma unroll
    for (int fn = 0; fn < 4; ++fn)
#pragma unroll
      for (int r = 0; r < 4; ++r)
        Plds[swz(wid * 16 + l4 * 4 + r, fn * 16 + l15)] = f2bf(p[fn][r]);

    // wave-private region: completion wait only, no barrier
    asm volatile("s_waitcnt lgkmcnt(0)" ::: "memory");

    // ---- O += P V ----
    __builtin_amdgcn_s_setprio(1);
#pragma unroll
    for (int kh = 0; kh < 2; ++kh) {
      bf16x8 ap = *(const bf16x8*)&Plds[swz(wid * 16 + l15, kh * 32 + l4 * 8)];
#pragma unroll
      for (int fn = 0; fn < 4; ++fn) {
        bf16x8 bv = *(const bf16x8*)&Vt[swz(fn * 16 + l15, kh * 32 + l4 * 8)];
        oacc[fn] = __builtin_amdgcn_mfma_f32_16x16x32_bf16(ap, bv, oacc[fn], 0, 0, 0);
      }
    }
    __builtin_amdgcn_s_setprio(0);
  }

  // ---- finalize: reduce lrun across the 16 lanes of each row, write in-place ----
#pragma unroll
  for (int r = 0; r < 4; ++r) {
    float su = lrun[r];
#pragma unroll
    for (int d = 1; d < 16; d <<= 1) su += __shfl_xor(su, d, 64);
    lrun[r] = 1.0f / su;
  }
  short* orow = qp + base + (size_t)(q0 + wid * 16) * CDIM;
#pragma unroll
  for (int fn = 0; fn < 4; ++fn)
#pragma unroll
    for (int r = 0; r < 4; ++r)
      orow[(size_t)(l4 * 4 + r) * CDIM + fn * 16 + l15] = f2bf(oacc[fn][r] * lrun[r]);
}

extern "C" void kernel_launch(void* const* d_in, const int* in_sizes, int n_in,
                              void* d_out, int out_size, void* d_ws, size_t ws_size,
                              hipStream_t stream) {
  const float* q  = (const float*)d_in[0];
  const float* k  = (const float*)d_in[1];
  const float* v  = (const float*)d_in[2];
  const float* Wq = (const float*)d_in[3];
  const float* Wk = (const float*)d_in[4];
  const float* Wv = (const float*)d_in[5];
  const float* Wo = (const float*)d_in[6];
  float* out = (float*)d_out;

  short* wbf = (short*)d_ws;                  // [Wq|Wk|Wv|Wo] bf16, 4 * 2^20 elems
  short* qp = wbf + (size_t)4 * WELEM;        // [4096][1024] bf16 (attn writes output in-place)
  short* kp = qp + (size_t)NTOK * CDIM;
  short* vp = kp + (size_t)NTOK * CDIM;
  // total ws use: (4 + 12) * 2^20 * 2B = 33.6 MB

  convw_kernel<<<512, 256, 0, stream>>>(Wq, Wk, Wv, Wo, wbf);
  proj_kernel<<<dim3(32, 24), 256, 0, stream>>>(q, k, v, wbf, qp, kp, vp);
  attn_kernel<<<dim3(32, 32), 256, 0, stream>>>(kp, vp, qp);
  out_kernel<<<dim3(32, 16), 256, 0, stream>>>(qp, wbf + (size_t)3 * WELEM, out);
}

// Round 5
// 184.222 us; speedup vs baseline: 1.4848x; 1.1135x over previous
//
#include <hip/hip_runtime.h>
#include <hip/hip_bf16.h>
#include <stdint.h>

typedef __attribute__((ext_vector_type(8))) short bf16x8;
typedef __attribute__((ext_vector_type(4))) float f32x4;
typedef __attribute__((ext_vector_type(16))) float f32x16;
typedef __attribute__((ext_vector_type(2))) uint32_t u32x2;
typedef __attribute__((ext_vector_type(4))) uint32_t u32x4;

#define LQ 2048
#define CDIM 1024
#define NTOK 4096
#define WELEM 1048576

__device__ __forceinline__ short f2bf(float f) {
  union { float f; uint32_t u; } v; v.f = f;
  uint32_t r = v.u + 0x7fffu + ((v.u >> 16) & 1u);
  return (short)(r >> 16);
}

__device__ __forceinline__ uint32_t cvt_pk_bf16(float a, float b) {
  uint32_t r;
  asm("v_cvt_pk_bf16_f32 %0, %1, %2" : "=v"(r) : "v"(a), "v"(b));
  return r;
}

// XOR swizzle for [rows][64] bf16 LDS tiles
__device__ __forceinline__ int swz(int row, int col) {
  return (row << 6) + (col ^ ((row & 7) << 3));
}

// global -> LDS direct copy, 16B per lane.
__device__ __forceinline__ void gl_lds16(const void* g, void* lds) {
  __builtin_amdgcn_global_load_lds(
      (const __attribute__((address_space(1))) void*)g,
      (__attribute__((address_space(3))) void*)lds, 16, 0, 0);
}

// v_permlane32_swap_b32: upper 32 lanes of a exchanged with lower 32 lanes of b.
__device__ __forceinline__ void plswap(uint32_t& a, uint32_t& b) {
  asm volatile("s_nop 1\n\tv_permlane32_swap_b32 %0, %1\n\ts_nop 1" : "+v"(a), "+v"(b));
}

// Build PV B-fragment (8 bf16 = P[q=lane&31][kv_rel=(lane>>5)*8+j]) from 8 per-lane
// P values p[r] = P[q=lane&31][kv_rel=(r&3)+8*(r>>2)+4*hi].
__device__ __forceinline__ bf16x8 mkfrag(const float* p) {
  uint32_t w0 = cvt_pk_bf16(p[0], p[1]);
  uint32_t w1 = cvt_pk_bf16(p[2], p[3]);
  uint32_t w2 = cvt_pk_bf16(p[4], p[5]);
  uint32_t w3 = cvt_pk_bf16(p[6], p[7]);
  plswap(w0, w2);
  plswap(w1, w3);
  union { u32x4 u; bf16x8 h; } cv;
  cv.u = u32x4{w0, w1, w2, w3};
  return cv.h;
}

// ---------------- weight fp32 -> bf16 convert ----------------
__global__ __launch_bounds__(256) void convw_kernel(const float* __restrict__ wq, const float* __restrict__ wk,
                                                    const float* __restrict__ wv, const float* __restrict__ wo,
                                                    short* __restrict__ dst) {
  const int NG = (4 * WELEM) / 8;
  for (int i = blockIdx.x * 256 + threadIdx.x; i < NG; i += gridDim.x * 256) {
    int e = i * 8;
    int seg = e >> 20;
    int off = e & (WELEM - 1);
    const float* s = seg == 0 ? wq : seg == 1 ? wk : seg == 2 ? wv : wo;
    f32x4 x0 = *(const f32x4*)(s + off);
    f32x4 x1 = *(const f32x4*)(s + off + 4);
    u32x4 r = { cvt_pk_bf16(x0[0], x0[1]), cvt_pk_bf16(x0[2], x0[3]),
                cvt_pk_bf16(x1[0], x1[1]), cvt_pk_bf16(x1[2], x1[3]) };
    *(u32x4*)(dst + e) = r;
  }
}

// ---------------- GEMM core: C[m][n] = sum_k A[m][k] B[n][k] ----------------
template<bool A_BF16, bool OUT_BF16, int BN>
__device__ __forceinline__ void gemm_core(const void* Ap, const short* __restrict__ Bp,
                                          void* Cp, int m0, int n0, int K, int ldc)
{
  __shared__ alignas(16) short Alds[128 * 64];
  __shared__ alignas(16) short Blds[BN * 64];

  const int t = threadIdx.x;
  const int lane = t & 63;
  const int wid = t >> 6;
  const int l15 = lane & 15, l4 = lane >> 4;
  constexpr int NI = (BN == 128) ? 4 : 2;
  const int wr = (BN == 128) ? (wid >> 1) * 64 : wid * 32;
  const int wc = (BN == 128) ? (wid & 1) * 64 : 0;

  f32x4 acc[NI][4];
#pragma unroll
  for (int i = 0; i < NI; ++i)
#pragma unroll
    for (int j = 0; j < 4; ++j) acc[i][j] = f32x4{0.f, 0.f, 0.f, 0.f};

  const int grow = lane >> 3;
  const int gcol = (lane & 7) * 8;
  constexpr int BI = BN / 32;
  const short* bsrc = Bp + (size_t)(n0 + wid * (BN / 4) + grow) * K + gcol;
  const short* asrcb = (const short*)Ap + (size_t)(m0 + wid * 32 + grow) * K + gcol;
  const int srow = t >> 1, scol = (t & 1) * 32;
  const float* asrcf = (const float*)Ap + (size_t)(m0 + srow) * K + scol;

  for (int k0 = 0; k0 < K; k0 += 64) {
    __syncthreads();
#pragma unroll
    for (int c = 0; c < BI; ++c)
      gl_lds16(bsrc + (size_t)c * 8 * K + k0, &Blds[(wid * BI + c) * 512]);
    if (A_BF16) {
#pragma unroll
      for (int c = 0; c < 4; ++c)
        gl_lds16(asrcb + (size_t)c * 8 * K + k0, &Alds[(wid * 4 + c) * 512]);
    } else {
      const float* ag = asrcf + k0;
#pragma unroll
      for (int cc = 0; cc < 4; ++cc) {
        f32x4 x0 = *(const f32x4*)(ag + cc * 8);
        f32x4 x1 = *(const f32x4*)(ag + cc * 8 + 4);
        u32x4 r = { cvt_pk_bf16(x0[0], x0[1]), cvt_pk_bf16(x0[2], x0[3]),
                    cvt_pk_bf16(x1[0], x1[1]), cvt_pk_bf16(x1[2], x1[3]) };
        *(u32x4*)&Alds[swz(srow, scol + cc * 8)] = r;
      }
    }
    __syncthreads();
#pragma unroll
    for (int kh = 0; kh < 2; ++kh) {
      bf16x8 af[NI], bfr[4];
#pragma unroll
      for (int i = 0; i < NI; ++i) {
        int row = wr + i * 16 + l15;
        af[i] = A_BF16 ? *(const bf16x8*)&Alds[row * 64 + kh * 32 + l4 * 8]
                       : *(const bf16x8*)&Alds[swz(row, kh * 32 + l4 * 8)];
      }
#pragma unroll
      for (int j = 0; j < 4; ++j)
        bfr[j] = *(const bf16x8*)&Blds[(wc + j * 16 + l15) * 64 + kh * 32 + l4 * 8];
      __builtin_amdgcn_s_setprio(1);
#pragma unroll
      for (int i = 0; i < NI; ++i)
#pragma unroll
        for (int j = 0; j < 4; ++j)
          acc[i][j] = __builtin_amdgcn_mfma_f32_16x16x32_bf16(af[i], bfr[j], acc[i][j], 0, 0, 0);
      __builtin_amdgcn_s_setprio(0);
    }
  }
#pragma unroll
  for (int i = 0; i < NI; ++i)
#pragma unroll
    for (int j = 0; j < 4; ++j)
#pragma unroll
      for (int r = 0; r < 4; ++r) {
        int rr = m0 + wr + i * 16 + l4 * 4 + r;
        int cc = n0 + wc + j * 16 + l15;
        if (OUT_BF16) ((short*)Cp)[(size_t)rr * ldc + cc] = f2bf(acc[i][j][r]);
        else          ((float*)Cp)[(size_t)rr * ldc + cc] = acc[i][j][r];
      }
}

__global__ __launch_bounds__(256) void proj_kernel(const float* __restrict__ q, const float* __restrict__ k,
                                                   const float* __restrict__ v, const short* __restrict__ wbf,
                                                   short* __restrict__ qp, short* __restrict__ kp,
                                                   short* __restrict__ vp)
{
  int nb = blockIdx.y;
  int sel = nb >> 3;
  int n0 = (nb & 7) * 128;
  int m0 = blockIdx.x * 128;
  const float* A = sel == 0 ? q : (sel == 1 ? k : v);
  const short* B = wbf + (size_t)sel * WELEM;
  short* C = sel == 0 ? qp : (sel == 1 ? kp : vp);
  gemm_core<false, true, 128>(A, B, C, m0, n0, CDIM, CDIM);
}

__global__ __launch_bounds__(256) void out_kernel(const short* __restrict__ at, const short* __restrict__ wo,
                                                  float* __restrict__ out)
{
  gemm_core<true, false, 64>(at, wo, out, blockIdx.x * 128, blockIdx.y * 64, CDIM, CDIM);
}

// ---------------- flash attention, 8-warp 32x32 swapped-QK^T ----------------
// Block = (bh, 256 q-rows); 8 waves x 32 q-rows. KVBLK=64. In-place output into qp.
// S^T = mfma(K,Q): lane holds S[kv=crow(r,hi)][q=lane&31]; softmax in-register;
// P -> B-frags via cvt_pk + permlane32_swap; O^T = mfma(V^T, P^T) keeps the
// q-column association (lane&31) so lrun normalization and the row-write are lane-local.
__global__ __launch_bounds__(512) void attn_kernel(const short* __restrict__ kp, const short* __restrict__ vp,
                                                   short* __restrict__ qp)
{
  __shared__ alignas(16) short Klds[64 * 64];   // [kv][d] swizzled
  __shared__ alignas(16) short Vt[64 * 64];     // [d][kv] swizzled (transposed on stage)

  const int bh = blockIdx.x;
  const int b = bh >> 4, h = bh & 15;
  const int q0 = blockIdx.y * 256;
  const int t = threadIdx.x, lane = t & 63, wid = t >> 6;
  const int l31 = lane & 31, hi = lane >> 5;
  const size_t base = (size_t)b * LQ * CDIM + (size_t)h * 64;
  const int qw = q0 + wid * 32;

  // Q B-fragments in registers: qf[ds] = Q[q=l31][ds*16 + hi*8 + j]
  bf16x8 qf[4];
  {
    const short* qrow = qp + base + (size_t)(qw + l31) * CDIM + hi * 8;
    qf[0] = *(const bf16x8*)(qrow);
    qf[1] = *(const bf16x8*)(qrow + 16);
    qf[2] = *(const bf16x8*)(qrow + 32);
    qf[3] = *(const bf16x8*)(qrow + 48);
  }

  f32x16 o0, o1;
#pragma unroll
  for (int r = 0; r < 16; ++r) { o0[r] = 0.f; o1[r] = 0.f; }
  float mrun = -1e30f;   // log2-domain running max (per q-row, replicated in lane pair)
  float lrun = 0.f;      // per-lane partial denominator (own 32 kv)

  const short* ksrc = kp + base + (size_t)(t >> 3) * CDIM + (t & 7) * 8;
  const int kdst = swz(t >> 3, (t & 7) * 8);
  const short* vsrc = vp + base + (size_t)(t & 63) * CDIM + wid * 8;
  const int vkv = t & 63, vd0 = wid * 8;

  const float SC2 = 0.18033688011112042f;  // log2(e)/sqrt(64)
  const float THR2 = 11.54f;               // 8*log2(e)

  for (int kt = 0; kt < LQ / 64; ++kt) {
    __syncthreads();
    {
      bf16x8 kv8 = *(const bf16x8*)ksrc;
      *(bf16x8*)&Klds[kdst] = kv8;
      bf16x8 vv = *(const bf16x8*)vsrc;
#pragma unroll
      for (int j = 0; j < 8; ++j) Vt[swz(vd0 + j, vkv)] = vv[j];
      ksrc += 64 * CDIM; vsrc += 64 * CDIM;
    }
    __syncthreads();

    // ---- S^T = K Q^T : c0 = kv 0..31, c1 = kv 32..63 (raw dots) ----
    f32x16 c0, c1;
#pragma unroll
    for (int r = 0; r < 16; ++r) { c0[r] = 0.f; c1[r] = 0.f; }
    __builtin_amdgcn_s_setprio(1);
#pragma unroll
    for (int ds = 0; ds < 4; ++ds) {
      bf16x8 ka = *(const bf16x8*)&Klds[swz(l31, ds * 16 + hi * 8)];
      bf16x8 kb = *(const bf16x8*)&Klds[swz(32 + l31, ds * 16 + hi * 8)];
      c0 = __builtin_amdgcn_mfma_f32_32x32x16_bf16(ka, qf[ds], c0, 0, 0, 0);
      c1 = __builtin_amdgcn_mfma_f32_32x32x16_bf16(kb, qf[ds], c1, 0, 0, 0);
    }
    __builtin_amdgcn_s_setprio(0);

    // ---- in-register online softmax (exp2 domain, defer-max) ----
    float m = fmaxf(c0[0], c1[0]);
#pragma unroll
    for (int r = 1; r < 16; ++r) m = fmaxf(m, fmaxf(c0[r], c1[r]));
    m = fmaxf(m, __shfl_xor(m, 32, 64));
    float mx2 = m * SC2;
    if (__any(mx2 > mrun + THR2)) {
      float mn = fmaxf(mrun, mx2);
      float cr = exp2f(mrun - mn);
      mrun = mn; lrun *= cr;
#pragma unroll
      for (int r = 0; r < 16; ++r) { o0[r] *= cr; o1[r] *= cr; }
    }
    float pr0[16], pr1[16];
    float s0 = 0.f, s1 = 0.f;
#pragma unroll
    for (int r = 0; r < 16; ++r) {
      pr0[r] = exp2f(fmaf(c0[r], SC2, -mrun));
      pr1[r] = exp2f(fmaf(c1[r], SC2, -mrun));
      s0 += pr0[r]; s1 += pr1[r];
    }
    lrun += s0 + s1;

    // ---- P -> B-fragments, fully in-register ----
    bf16x8 pa0 = mkfrag(pr0);       // kv 0..15
    bf16x8 pa1 = mkfrag(pr0 + 8);   // kv 16..31
    bf16x8 pa2 = mkfrag(pr1);       // kv 32..47
    bf16x8 pa3 = mkfrag(pr1 + 8);   // kv 48..63

    // ---- O^T += V^T P^T  (A = V-frag, B = P-frag: lane keeps q=l31 column) ----
    __builtin_amdgcn_s_setprio(1);
#pragma unroll
    for (int ks = 0; ks < 4; ++ks) {
      bf16x8 pa = ks == 0 ? pa0 : ks == 1 ? pa1 : ks == 2 ? pa2 : pa3;
      bf16x8 v0 = *(const bf16x8*)&Vt[swz(l31, ks * 16 + hi * 8)];
      bf16x8 v1 = *(const bf16x8*)&Vt[swz(32 + l31, ks * 16 + hi * 8)];
      o0 = __builtin_amdgcn_mfma_f32_32x32x16_bf16(v0, pa, o0, 0, 0, 0);
      o1 = __builtin_amdgcn_mfma_f32_32x32x16_bf16(v1, pa, o1, 0, 0, 0);
    }
    __builtin_amdgcn_s_setprio(0);
  }

  // ---- finalize: o0[r] = O[q=l31][d=crow(r,hi)], o1 -> d+32 ----
  float tot = lrun + __shfl_xor(lrun, 32, 64);
  float inv = 1.0f / tot;
  short* orow = qp + base + (size_t)(qw + l31) * CDIM;
#pragma unroll
  for (int rq = 0; rq < 4; ++rq) {
    u32x2 w;
    w[0] = cvt_pk_bf16(o0[rq * 4 + 0] * inv, o0[rq * 4 + 1] * inv);
    w[1] = cvt_pk_bf16(o0[rq * 4 + 2] * inv, o0[rq * 4 + 3] * inv);
    *(u32x2*)(orow + rq * 8 + hi * 4) = w;
    w[0] = cvt_pk_bf16(o1[rq * 4 + 0] * inv, o1[rq * 4 + 1] * inv);
    w[1] = cvt_pk_bf16(o1[rq * 4 + 2] * inv, o1[rq * 4 + 3] * inv);
    *(u32x2*)(orow + 32 + rq * 8 + hi * 4) = w;
  }
}

extern "C" void kernel_launch(void* const* d_in, const int* in_sizes, int n_in,
                              void* d_out, int out_size, void* d_ws, size_t ws_size,
                              hipStream_t stream) {
  const float* q  = (const float*)d_in[0];
  const float* k  = (const float*)d_in[1];
  const float* v  = (const float*)d_in[2];
  const float* Wq = (const float*)d_in[3];
  const float* Wk = (const float*)d_in[4];
  const float* Wv = (const float*)d_in[5];
  const float* Wo = (const float*)d_in[6];
  float* out = (float*)d_out;

  short* wbf = (short*)d_ws;                  // [Wq|Wk|Wv|Wo] bf16
  short* qp = wbf + (size_t)4 * WELEM;        // attn writes output in-place
  short* kp = qp + (size_t)NTOK * CDIM;
  short* vp = kp + (size_t)NTOK * CDIM;

  convw_kernel<<<512, 256, 0, stream>>>(Wq, Wk, Wv, Wo, wbf);
  proj_kernel<<<dim3(32, 24), 256, 0, stream>>>(q, k, v, wbf, qp, kp, vp);
  attn_kernel<<<dim3(32, 8), 512, 0, stream>>>(kp, vp, qp);
  out_kernel<<<dim3(32, 16), 256, 0, stream>>>(qp, wbf + (size_t)3 * WELEM, out);
}

// Round 6
// 178.650 us; speedup vs baseline: 1.5311x; 1.0312x over previous
//
#include <hip/hip_runtime.h>
#include <hip/hip_bf16.h>
#include <stdint.h>

typedef __attribute__((ext_vector_type(8))) short bf16x8;
typedef __attribute__((ext_vector_type(4))) float f32x4;
typedef __attribute__((ext_vector_type(16))) float f32x16;
typedef __attribute__((ext_vector_type(2))) uint32_t u32x2;
typedef __attribute__((ext_vector_type(4))) uint32_t u32x4;

#define LQ 2048
#define CDIM 1024
#define NTOK 4096
#define WELEM 1048576

__device__ __forceinline__ short f2bf(float f) {
  union { float f; uint32_t u; } v; v.f = f;
  uint32_t r = v.u + 0x7fffu + ((v.u >> 16) & 1u);
  return (short)(r >> 16);
}

__device__ __forceinline__ uint32_t cvt_pk_bf16(float a, float b) {
  uint32_t r;
  asm("v_cvt_pk_bf16_f32 %0, %1, %2" : "=v"(r) : "v"(a), "v"(b));
  return r;
}

// XOR swizzle for [rows][64] bf16 LDS tiles
__device__ __forceinline__ int swz(int row, int col) {
  return (row << 6) + (col ^ ((row & 7) << 3));
}

// global -> LDS direct copy, 16B per lane (LDS dest = wave-uniform base + lane*16).
__device__ __forceinline__ void gl_lds16(const void* g, void* lds) {
  __builtin_amdgcn_global_load_lds(
      (const __attribute__((address_space(1))) void*)g,
      (__attribute__((address_space(3))) void*)lds, 16, 0, 0);
}

// v_permlane32_swap_b32: upper 32 lanes of a exchanged with lower 32 lanes of b.
__device__ __forceinline__ void plswap(uint32_t& a, uint32_t& b) {
  asm volatile("s_nop 1\n\tv_permlane32_swap_b32 %0, %1\n\ts_nop 1" : "+v"(a), "+v"(b));
}

// Build PV B-fragment (8 bf16 = P[q=lane&31][kv_rel=(lane>>5)*8+j]) from 8 per-lane
// P values p[r] = P[q=lane&31][kv_rel=(r&3)+8*(r>>2)+4*hi].
__device__ __forceinline__ bf16x8 mkfrag(const float* p) {
  uint32_t w0 = cvt_pk_bf16(p[0], p[1]);
  uint32_t w1 = cvt_pk_bf16(p[2], p[3]);
  uint32_t w2 = cvt_pk_bf16(p[4], p[5]);
  uint32_t w3 = cvt_pk_bf16(p[6], p[7]);
  plswap(w0, w2);
  plswap(w1, w3);
  union { u32x4 u; bf16x8 h; } cv;
  cv.u = u32x4{w0, w1, w2, w3};
  return cv.h;
}

// ---------------- weight fp32 -> bf16 convert ----------------
__global__ __launch_bounds__(256) void convw_kernel(const float* __restrict__ wq, const float* __restrict__ wk,
                                                    const float* __restrict__ wv, const float* __restrict__ wo,
                                                    short* __restrict__ dst) {
  const int NG = (4 * WELEM) / 8;
  for (int i = blockIdx.x * 256 + threadIdx.x; i < NG; i += gridDim.x * 256) {
    int e = i * 8;
    int seg = e >> 20;
    int off = e & (WELEM - 1);
    const float* s = seg == 0 ? wq : seg == 1 ? wk : seg == 2 ? wv : wo;
    f32x4 x0 = *(const f32x4*)(s + off);
    f32x4 x1 = *(const f32x4*)(s + off + 4);
    u32x4 r = { cvt_pk_bf16(x0[0], x0[1]), cvt_pk_bf16(x0[2], x0[3]),
                cvt_pk_bf16(x1[0], x1[1]), cvt_pk_bf16(x1[2], x1[3]) };
    *(u32x4*)(dst + e) = r;
  }
}

// ---------------- GEMM core: C[m][n] = sum_k A[m][k] B[n][k] ----------------
template<bool A_BF16, bool OUT_BF16, int BN>
__device__ __forceinline__ void gemm_core(const void* Ap, const short* __restrict__ Bp,
                                          void* Cp, int m0, int n0, int K, int ldc)
{
  __shared__ alignas(16) short Alds[128 * 64];
  __shared__ alignas(16) short Blds[BN * 64];

  const int t = threadIdx.x;
  const int lane = t & 63;
  const int wid = t >> 6;
  const int l15 = lane & 15, l4 = lane >> 4;
  constexpr int NI = (BN == 128) ? 4 : 2;
  const int wr = (BN == 128) ? (wid >> 1) * 64 : wid * 32;
  const int wc = (BN == 128) ? (wid & 1) * 64 : 0;

  f32x4 acc[NI][4];
#pragma unroll
  for (int i = 0; i < NI; ++i)
#pragma unroll
    for (int j = 0; j < 4; ++j) acc[i][j] = f32x4{0.f, 0.f, 0.f, 0.f};

  const int grow = lane >> 3;
  const int gcol = (lane & 7) * 8;
  constexpr int BI = BN / 32;
  const short* bsrc = Bp + (size_t)(n0 + wid * (BN / 4) + grow) * K + gcol;
  const short* asrcb = (const short*)Ap + (size_t)(m0 + wid * 32 + grow) * K + gcol;
  const int srow = t >> 1, scol = (t & 1) * 32;
  const float* asrcf = (const float*)Ap + (size_t)(m0 + srow) * K + scol;

  for (int k0 = 0; k0 < K; k0 += 64) {
    __syncthreads();
#pragma unroll
    for (int c = 0; c < BI; ++c)
      gl_lds16(bsrc + (size_t)c * 8 * K + k0, &Blds[(wid * BI + c) * 512]);
    if (A_BF16) {
#pragma unroll
      for (int c = 0; c < 4; ++c)
        gl_lds16(asrcb + (size_t)c * 8 * K + k0, &Alds[(wid * 4 + c) * 512]);
    } else {
      const float* ag = asrcf + k0;
#pragma unroll
      for (int cc = 0; cc < 4; ++cc) {
        f32x4 x0 = *(const f32x4*)(ag + cc * 8);
        f32x4 x1 = *(const f32x4*)(ag + cc * 8 + 4);
        u32x4 r = { cvt_pk_bf16(x0[0], x0[1]), cvt_pk_bf16(x0[2], x0[3]),
                    cvt_pk_bf16(x1[0], x1[1]), cvt_pk_bf16(x1[2], x1[3]) };
        *(u32x4*)&Alds[swz(srow, scol + cc * 8)] = r;
      }
    }
    __syncthreads();
#pragma unroll
    for (int kh = 0; kh < 2; ++kh) {
      bf16x8 af[NI], bfr[4];
#pragma unroll
      for (int i = 0; i < NI; ++i) {
        int row = wr + i * 16 + l15;
        af[i] = A_BF16 ? *(const bf16x8*)&Alds[row * 64 + kh * 32 + l4 * 8]
                       : *(const bf16x8*)&Alds[swz(row, kh * 32 + l4 * 8)];
      }
#pragma unroll
      for (int j = 0; j < 4; ++j)
        bfr[j] = *(const bf16x8*)&Blds[(wc + j * 16 + l15) * 64 + kh * 32 + l4 * 8];
      __builtin_amdgcn_s_setprio(1);
#pragma unroll
      for (int i = 0; i < NI; ++i)
#pragma unroll
        for (int j = 0; j < 4; ++j)
          acc[i][j] = __builtin_amdgcn_mfma_f32_16x16x32_bf16(af[i], bfr[j], acc[i][j], 0, 0, 0);
      __builtin_amdgcn_s_setprio(0);
    }
  }
#pragma unroll
  for (int i = 0; i < NI; ++i)
#pragma unroll
    for (int j = 0; j < 4; ++j)
#pragma unroll
      for (int r = 0; r < 4; ++r) {
        int rr = m0 + wr + i * 16 + l4 * 4 + r;
        int cc = n0 + wc + j * 16 + l15;
        if (OUT_BF16) ((short*)Cp)[(size_t)rr * ldc + cc] = f2bf(acc[i][j][r]);
        else          ((float*)Cp)[(size_t)rr * ldc + cc] = acc[i][j][r];
      }
}

__global__ __launch_bounds__(256) void proj_kernel(const float* __restrict__ q, const float* __restrict__ k,
                                                   const float* __restrict__ v, const short* __restrict__ wbf,
                                                   short* __restrict__ qp, short* __restrict__ kp,
                                                   short* __restrict__ vp)
{
  int nb = blockIdx.y;
  int sel = nb >> 3;
  int n0 = (nb & 7) * 128;
  int m0 = blockIdx.x * 128;
  const float* A = sel == 0 ? q : (sel == 1 ? k : v);
  const short* B = wbf + (size_t)sel * WELEM;
  short* C = sel == 0 ? qp : (sel == 1 ? kp : vp);
  gemm_core<false, true, 128>(A, B, C, m0, n0, CDIM, CDIM);
}

__global__ __launch_bounds__(256) void out_kernel(const short* __restrict__ at, const short* __restrict__ wo,
                                                  float* __restrict__ out)
{
  gemm_core<true, false, 64>(at, wo, out, blockIdx.x * 128, blockIdx.y * 64, CDIM, CDIM);
}

// ---------------- flash attention, 4-wave QBLK=128, double-buffered prefetch ----------------
// Grid (bh=32, qt=16) -> 512 blocks = 2 blocks/CU; one barrier per KV-tile.
// K staged via PRE-SWIZZLED-source global_load_lds (src chunk = (l&7)^(l>>3), XOR
// involution; reader uses swz unchanged). V prefetched global->regs early, transposed
// b16 LDS writes late (T14). Stage(t+1) issued after the iter-t barrier => safe:
// all waves finished reading buf^1 (iter t-1) before any write to it.
__global__ __launch_bounds__(256) void attn_kernel(const short* __restrict__ kp, const short* __restrict__ vp,
                                                   short* __restrict__ qp)
{
  __shared__ alignas(16) short Kbuf[2][64 * 64];  // [kv][d] swizzled
  __shared__ alignas(16) short Vbuf[2][64 * 64];  // [d][kv] swizzled (transposed)

  const int bh = blockIdx.x;
  const int b = bh >> 4, h = bh & 15;
  const int q0 = blockIdx.y * 128;
  const int t = threadIdx.x, lane = t & 63, wid = t >> 6;
  const int l31 = lane & 31, hi = lane >> 5;
  const size_t base = (size_t)b * LQ * CDIM + (size_t)h * 64;
  const int qw = q0 + wid * 32;

  // Q B-fragments in registers: qf[ds] = Q[q=l31][ds*16 + hi*8 + j]
  bf16x8 qf[4];
  {
    const short* qrow = qp + base + (size_t)(qw + l31) * CDIM + hi * 8;
    qf[0] = *(const bf16x8*)(qrow);
    qf[1] = *(const bf16x8*)(qrow + 16);
    qf[2] = *(const bf16x8*)(qrow + 32);
    qf[3] = *(const bf16x8*)(qrow + 48);
  }

  f32x16 o0, o1;
#pragma unroll
  for (int r = 0; r < 16; ++r) { o0[r] = 0.f; o1[r] = 0.f; }
  float mrun = -1e30f;
  float lrun = 0.f;

  // K staging: wave w stages rows w*16 + c*8 + (l>>3), pre-swizzled source chunk
  const int krow_in_grp = lane >> 3;                       // 0..7
  const int kchunk = (lane & 7) ^ krow_in_grp;             // pre-swizzled src chunk
  const short* ksrc0 = kp + base + (size_t)(wid * 16 + krow_in_grp) * CDIM + kchunk * 8;
  // V staging: lane owns kv column = lane, d-slice = wid*16..+15
  const int vd0 = wid * 16;
  const short* vsrc0 = vp + base + (size_t)lane * CDIM + vd0;

  const float SC2 = 0.18033688011112042f;  // log2(e)/sqrt(64)
  const float THR2 = 11.54f;               // 8*log2(e)
  const int NT = LQ / 64;

  bf16x8 vv0, vv1;
  // ---- prologue: stage tile 0 ----
  gl_lds16(ksrc0, &Kbuf[0][(wid * 16) * 64]);
  gl_lds16(ksrc0 + (size_t)8 * CDIM, &Kbuf[0][(wid * 16 + 8) * 64]);
  vv0 = *(const bf16x8*)(vsrc0);
  vv1 = *(const bf16x8*)(vsrc0 + 8);

  for (int kt = 0; kt < NT; ++kt) {
    const int cur = kt & 1;
    // all tile-kt global traffic (gl_lds K + V reg loads) complete
    asm volatile("s_waitcnt vmcnt(0)" ::: "memory");
    // late V write: regs -> transposed swizzled LDS
#pragma unroll
    for (int j = 0; j < 8; ++j) Vbuf[cur][swz(vd0 + j, lane)] = vv0[j];
#pragma unroll
    for (int j = 0; j < 8; ++j) Vbuf[cur][swz(vd0 + 8 + j, lane)] = vv1[j];
    __syncthreads();

    // ---- prefetch tile kt+1 into buf^1 / regs ----
    if (kt + 1 < NT) {
      const short* ks = ksrc0 + (size_t)(kt + 1) * 64 * CDIM;
      gl_lds16(ks, &Kbuf[cur ^ 1][(wid * 16) * 64]);
      gl_lds16(ks + (size_t)8 * CDIM, &Kbuf[cur ^ 1][(wid * 16 + 8) * 64]);
      const short* vs = vsrc0 + (size_t)(kt + 1) * 64 * CDIM;
      vv0 = *(const bf16x8*)(vs);
      vv1 = *(const bf16x8*)(vs + 8);
    }
    __builtin_amdgcn_sched_barrier(0);   // pin prefetch issue above compute

    // ---- S^T = K Q^T : c0 = kv 0..31, c1 = kv 32..63 ----
    const short* Klds = Kbuf[cur];
    const short* Vt = Vbuf[cur];
    f32x16 c0, c1;
#pragma unroll
    for (int r = 0; r < 16; ++r) { c0[r] = 0.f; c1[r] = 0.f; }
    __builtin_amdgcn_s_setprio(1);
#pragma unroll
    for (int ds = 0; ds < 4; ++ds) {
      bf16x8 ka = *(const bf16x8*)&Klds[swz(l31, ds * 16 + hi * 8)];
      bf16x8 kb = *(const bf16x8*)&Klds[swz(32 + l31, ds * 16 + hi * 8)];
      c0 = __builtin_amdgcn_mfma_f32_32x32x16_bf16(ka, qf[ds], c0, 0, 0, 0);
      c1 = __builtin_amdgcn_mfma_f32_32x32x16_bf16(kb, qf[ds], c1, 0, 0, 0);
    }
    __builtin_amdgcn_s_setprio(0);

    // ---- in-register online softmax (exp2 domain, defer-max) ----
    float m = fmaxf(c0[0], c1[0]);
#pragma unroll
    for (int r = 1; r < 16; ++r) m = fmaxf(m, fmaxf(c0[r], c1[r]));
    m = fmaxf(m, __shfl_xor(m, 32, 64));
    float mx2 = m * SC2;
    if (__any(mx2 > mrun + THR2)) {
      float mn = fmaxf(mrun, mx2);
      float cr = exp2f(mrun - mn);
      mrun = mn; lrun *= cr;
#pragma unroll
      for (int r = 0; r < 16; ++r) { o0[r] *= cr; o1[r] *= cr; }
    }
    float pr0[16], pr1[16];
    float s0 = 0.f, s1 = 0.f;
#pragma unroll
    for (int r = 0; r < 16; ++r) {
      pr0[r] = exp2f(fmaf(c0[r], SC2, -mrun));
      pr1[r] = exp2f(fmaf(c1[r], SC2, -mrun));
      s0 += pr0[r]; s1 += pr1[r];
    }
    lrun += s0 + s1;

    // ---- P -> B-fragments, fully in-register ----
    bf16x8 pa0 = mkfrag(pr0);
    bf16x8 pa1 = mkfrag(pr0 + 8);
    bf16x8 pa2 = mkfrag(pr1);
    bf16x8 pa3 = mkfrag(pr1 + 8);

    // ---- O^T += V^T P^T ----
    __builtin_amdgcn_s_setprio(1);
#pragma unroll
    for (int ks = 0; ks < 4; ++ks) {
      bf16x8 pa = ks == 0 ? pa0 : ks == 1 ? pa1 : ks == 2 ? pa2 : pa3;
      bf16x8 v0 = *(const bf16x8*)&Vt[swz(l31, ks * 16 + hi * 8)];
      bf16x8 v1 = *(const bf16x8*)&Vt[swz(32 + l31, ks * 16 + hi * 8)];
      o0 = __builtin_amdgcn_mfma_f32_32x32x16_bf16(v0, pa, o0, 0, 0, 0);
      o1 = __builtin_amdgcn_mfma_f32_32x32x16_bf16(v1, pa, o1, 0, 0, 0);
    }
    __builtin_amdgcn_s_setprio(0);
  }

  // ---- finalize: o0[r] = O[q=l31][d=crow(r,hi)], o1 -> d+32 ----
  float tot = lrun + __shfl_xor(lrun, 32, 64);
  float inv = 1.0f / tot;
  short* orow = qp + base + (size_t)(qw + l31) * CDIM;
#pragma unroll
  for (int rq = 0; rq < 4; ++rq) {
    u32x2 w;
    w[0] = cvt_pk_bf16(o0[rq * 4 + 0] * inv, o0[rq * 4 + 1] * inv);
    w[1] = cvt_pk_bf16(o0[rq * 4 + 2] * inv, o0[rq * 4 + 3] * inv);
    *(u32x2*)(orow + rq * 8 + hi * 4) = w;
    w[0] = cvt_pk_bf16(o1[rq * 4 + 0] * inv, o1[rq * 4 + 1] * inv);
    w[1] = cvt_pk_bf16(o1[rq * 4 + 2] * inv, o1[rq * 4 + 3] * inv);
    *(u32x2*)(orow + 32 + rq * 8 + hi * 4) = w;
  }
}

extern "C" void kernel_launch(void* const* d_in, const int* in_sizes, int n_in,
                              void* d_out, int out_size, void* d_ws, size_t ws_size,
                              hipStream_t stream) {
  const float* q  = (const float*)d_in[0];
  const float* k  = (const float*)d_in[1];
  const float* v  = (const float*)d_in[2];
  const float* Wq = (const float*)d_in[3];
  const float* Wk = (const float*)d_in[4];
  const float* Wv = (const float*)d_in[5];
  const float* Wo = (const float*)d_in[6];
  float* out = (float*)d_out;

  short* wbf = (short*)d_ws;                  // [Wq|Wk|Wv|Wo] bf16
  short* qp = wbf + (size_t)4 * WELEM;        // attn writes output in-place
  short* kp = qp + (size_t)NTOK * CDIM;
  short* vp = kp + (size_t)NTOK * CDIM;

  convw_kernel<<<512, 256, 0, stream>>>(Wq, Wk, Wv, Wo, wbf);
  proj_kernel<<<dim3(32, 24), 256, 0, stream>>>(q, k, v, wbf, qp, kp, vp);
  attn_kernel<<<dim3(32, 16), 256, 0, stream>>>(kp, vp, qp);
  out_kernel<<<dim3(32, 16), 256, 0, stream>>>(qp, wbf + (size_t)3 * WELEM, out);
}

// Round 7
// 142.143 us; speedup vs baseline: 1.9244x; 1.2568x over previous
//
#include <hip/hip_runtime.h>
#include <hip/hip_bf16.h>
#include <stdint.h>

typedef __attribute__((ext_vector_type(8))) short bf16x8;
typedef __attribute__((ext_vector_type(4))) float f32x4;
typedef __attribute__((ext_vector_type(16))) float f32x16;
typedef __attribute__((ext_vector_type(2))) uint32_t u32x2;
typedef __attribute__((ext_vector_type(4))) uint32_t u32x4;

#define LQ 2048
#define CDIM 1024
#define NTOK 4096
#define WELEM 1048576          // elems per weight matrix
#define TELEM 4194304          // elems per q/k/v tensor (4096*1024)

__device__ __forceinline__ short f2bf(float f) {
  union { float f; uint32_t u; } v; v.f = f;
  uint32_t r = v.u + 0x7fffu + ((v.u >> 16) & 1u);
  return (short)(r >> 16);
}

__device__ __forceinline__ uint32_t cvt_pk_bf16(float a, float b) {
  uint32_t r;
  asm("v_cvt_pk_bf16_f32 %0, %1, %2" : "=v"(r) : "v"(a), "v"(b));
  return r;
}

// XOR swizzle for [rows][64] bf16 LDS tiles
__device__ __forceinline__ int swz(int row, int col) {
  return (row << 6) + (col ^ ((row & 7) << 3));
}

// global -> LDS direct copy, 16B per lane (LDS dest = wave-uniform base + lane*16).
__device__ __forceinline__ void gl_lds16(const void* g, void* lds) {
  __builtin_amdgcn_global_load_lds(
      (const __attribute__((address_space(1))) void*)g,
      (__attribute__((address_space(3))) void*)lds, 16, 0, 0);
}

// v_permlane32_swap_b32: upper 32 lanes of a exchanged with lower 32 lanes of b.
__device__ __forceinline__ void plswap(uint32_t& a, uint32_t& b) {
  asm volatile("s_nop 1\n\tv_permlane32_swap_b32 %0, %1\n\ts_nop 1" : "+v"(a), "+v"(b));
}

// Build PV B-fragment (8 bf16 = P[q=lane&31][kv_rel=(lane>>5)*8+j]) from 8 per-lane
// P values p[r] = P[q=lane&31][kv_rel=(r&3)+8*(r>>2)+4*hi].
__device__ __forceinline__ bf16x8 mkfrag(const float* p) {
  uint32_t w0 = cvt_pk_bf16(p[0], p[1]);
  uint32_t w1 = cvt_pk_bf16(p[2], p[3]);
  uint32_t w2 = cvt_pk_bf16(p[4], p[5]);
  uint32_t w3 = cvt_pk_bf16(p[6], p[7]);
  plswap(w0, w2);
  plswap(w1, w3);
  union { u32x4 u; bf16x8 h; } cv;
  cv.u = u32x4{w0, w1, w2, w3};
  return cv.h;
}

// ---------------- fp32 -> bf16 convert: 4 weights + q,k,v ----------------
__global__ __launch_bounds__(256) void convall_kernel(const float* __restrict__ wq, const float* __restrict__ wk,
                                                      const float* __restrict__ wv, const float* __restrict__ wo,
                                                      const float* __restrict__ q, const float* __restrict__ k,
                                                      const float* __restrict__ v,
                                                      short* __restrict__ wbf, short* __restrict__ qb,
                                                      short* __restrict__ kb, short* __restrict__ vb) {
  const int NG = (4 * WELEM + 3 * TELEM) / 8;   // 2M groups of 8
  for (int i = blockIdx.x * 256 + threadIdx.x; i < NG; i += gridDim.x * 256) {
    int e = i * 8;
    const float* s;
    short* d;
    if (e < 4 * WELEM) {
      int seg = e >> 20;
      int off = e & (WELEM - 1);
      s = (seg == 0 ? wq : seg == 1 ? wk : seg == 2 ? wv : wo) + off;
      d = wbf + e;
    } else {
      int j = e - 4 * WELEM;
      int which = j >> 22;
      int off = j & (TELEM - 1);
      s = (which == 0 ? q : which == 1 ? k : v) + off;
      d = (which == 0 ? qb : which == 1 ? kb : vb) + off;
    }
    f32x4 x0 = *(const f32x4*)(s);
    f32x4 x1 = *(const f32x4*)(s + 4);
    u32x4 r = { cvt_pk_bf16(x0[0], x0[1]), cvt_pk_bf16(x0[2], x0[3]),
                cvt_pk_bf16(x1[0], x1[1]), cvt_pk_bf16(x1[2], x1[3]) };
    *(u32x4*)(d) = r;
  }
}

// ---------------- GEMM core (all-bf16): C[m][n] = sum_k A[m][k] B[n][k] ----------------
// 128 x BN tile, BK=64. Both operands via global_load_lds into DOUBLE-BUFFERED,
// PRE-SWIZZLED LDS (src chunk = (l&7)^(l>>3); reads use swz). Counted vmcnt (never 0
// mid-loop) + raw s_barrier keep next tile's DMA in flight across the barrier.
template<bool OUT_BF16, int BN>
__device__ __forceinline__ void gemm_bb(const short* __restrict__ Ap, const short* __restrict__ Bp,
                                        void* Cp, int m0, int n0, int K, int ldc)
{
  __shared__ alignas(16) short Ab[2][128 * 64];
  __shared__ alignas(16) short Bb[2][BN * 64];

  const int t = threadIdx.x;
  const int lane = t & 63;
  const int wid = t >> 6;
  const int l15 = lane & 15, l4 = lane >> 4;
  constexpr int NI = (BN == 128) ? 4 : 2;
  const int wr = (BN == 128) ? (wid >> 1) * 64 : wid * 32;
  const int wc = (BN == 128) ? (wid & 1) * 64 : 0;

  f32x4 acc[NI][4];
#pragma unroll
  for (int i = 0; i < NI; ++i)
#pragma unroll
    for (int j = 0; j < 4; ++j) acc[i][j] = f32x4{0.f, 0.f, 0.f, 0.f};

  const int grow = lane >> 3;                  // row within 8-row group
  const int gcol = ((lane & 7) ^ grow) * 8;    // pre-swizzled source chunk
  constexpr int AI = 4, BI = BN / 32;
  const short* asrc = Ap + (size_t)(m0 + wid * 32 + grow) * K + gcol;
  const short* bsrc = Bp + (size_t)(n0 + wid * (BN / 4) + grow) * K + gcol;

  // prologue: stage tile 0
#pragma unroll
  for (int c = 0; c < AI; ++c) gl_lds16(asrc + (size_t)c * 8 * K, &Ab[0][(wid * AI + c) * 512]);
#pragma unroll
  for (int c = 0; c < BI; ++c) gl_lds16(bsrc + (size_t)c * 8 * K, &Bb[0][(wid * BI + c) * 512]);

  const int NT = K / 64;
  for (int kt = 0; kt < NT; ++kt) {
    const int cur = kt & 1;
    if (kt + 1 < NT) {
      const short* a2 = asrc + (size_t)(kt + 1) * 64;
      const short* b2 = bsrc + (size_t)(kt + 1) * 64;
#pragma unroll
      for (int c = 0; c < AI; ++c) gl_lds16(a2 + (size_t)c * 8 * K, &Ab[cur ^ 1][(wid * AI + c) * 512]);
#pragma unroll
      for (int c = 0; c < BI; ++c) gl_lds16(b2 + (size_t)c * 8 * K, &Bb[cur ^ 1][(wid * BI + c) * 512]);
      // wait tile-kt's 8 (or 6) DMAs; keep tile kt+1 in flight
      if constexpr (BN == 128) asm volatile("s_waitcnt vmcnt(8)" ::: "memory");
      else                     asm volatile("s_waitcnt vmcnt(6)" ::: "memory");
    } else {
      asm volatile("s_waitcnt vmcnt(0)" ::: "memory");
    }
    __builtin_amdgcn_sched_barrier(0);
    __builtin_amdgcn_s_barrier();          // all waves' tile-kt portions landed
    __builtin_amdgcn_sched_barrier(0);

    const short* Al = Ab[cur];
    const short* Bl = Bb[cur];
#pragma unroll
    for (int kh = 0; kh < 2; ++kh) {
      bf16x8 af[NI], bfr[4];
#pragma unroll
      for (int i = 0; i < NI; ++i)
        af[i] = *(const bf16x8*)&Al[swz(wr + i * 16 + l15, kh * 32 + l4 * 8)];
#pragma unroll
      for (int j = 0; j < 4; ++j)
        bfr[j] = *(const bf16x8*)&Bl[swz(wc + j * 16 + l15, kh * 32 + l4 * 8)];
      __builtin_amdgcn_s_setprio(1);
#pragma unroll
      for (int i = 0; i < NI; ++i)
#pragma unroll
        for (int j = 0; j < 4; ++j)
          acc[i][j] = __builtin_amdgcn_mfma_f32_16x16x32_bf16(af[i], bfr[j], acc[i][j], 0, 0, 0);
      __builtin_amdgcn_s_setprio(0);
    }
    __builtin_amdgcn_sched_barrier(0);
    __builtin_amdgcn_s_barrier();          // all waves done reading before next DMA overwrite
  }

#pragma unroll
  for (int i = 0; i < NI; ++i)
#pragma unroll
    for (int j = 0; j < 4; ++j)
#pragma unroll
      for (int r = 0; r < 4; ++r) {
        int rr = m0 + wr + i * 16 + l4 * 4 + r;
        int cc = n0 + wc + j * 16 + l15;
        if (OUT_BF16) ((short*)Cp)[(size_t)rr * ldc + cc] = f2bf(acc[i][j][r]);
        else          ((float*)Cp)[(size_t)rr * ldc + cc] = acc[i][j][r];
      }
}

__global__ __launch_bounds__(256) void proj_kernel(const short* __restrict__ qb, const short* __restrict__ kb,
                                                   const short* __restrict__ vb, const short* __restrict__ wbf,
                                                   short* __restrict__ qp, short* __restrict__ kp,
                                                   short* __restrict__ vp)
{
  int nb = blockIdx.y;
  int sel = nb >> 3;
  int n0 = (nb & 7) * 128;
  int m0 = blockIdx.x * 128;
  const short* A = sel == 0 ? qb : (sel == 1 ? kb : vb);
  const short* B = wbf + (size_t)sel * WELEM;
  short* C = sel == 0 ? qp : (sel == 1 ? kp : vp);
  gemm_bb<true, 128>(A, B, C, m0, n0, CDIM, CDIM);
}

__global__ __launch_bounds__(256) void out_kernel(const short* __restrict__ at, const short* __restrict__ wo,
                                                  float* __restrict__ out)
{
  gemm_bb<false, 64>(at, wo, out, blockIdx.x * 128, blockIdx.y * 64, CDIM, CDIM);
}

// ---------------- flash attention, 4-wave QBLK=128, double-buffered prefetch ----------------
// Row denominators via MFMA-with-ones (lacc); max-reduce via v_max3-friendly triples.
__global__ __launch_bounds__(256) void attn_kernel(const short* __restrict__ kp, const short* __restrict__ vp,
                                                   short* __restrict__ qp)
{
  __shared__ alignas(16) short Kbuf[2][64 * 64];  // [kv][d] swizzled
  __shared__ alignas(16) short Vbuf[2][64 * 64];  // [d][kv] swizzled (transposed)

  const int bh = blockIdx.x;
  const int b = bh >> 4, h = bh & 15;
  const int q0 = blockIdx.y * 128;
  const int t = threadIdx.x, lane = t & 63, wid = t >> 6;
  const int l31 = lane & 31, hi = lane >> 5;
  const size_t base = (size_t)b * LQ * CDIM + (size_t)h * 64;
  const int qw = q0 + wid * 32;

  bf16x8 qf[4];
  {
    const short* qrow = qp + base + (size_t)(qw + l31) * CDIM + hi * 8;
    qf[0] = *(const bf16x8*)(qrow);
    qf[1] = *(const bf16x8*)(qrow + 16);
    qf[2] = *(const bf16x8*)(qrow + 32);
    qf[3] = *(const bf16x8*)(qrow + 48);
  }

  bf16x8 ones;
#pragma unroll
  for (int j = 0; j < 8; ++j) ones[j] = (short)0x3F80;   // bf16 1.0

  f32x16 o0, o1, lacc;
#pragma unroll
  for (int r = 0; r < 16; ++r) { o0[r] = 0.f; o1[r] = 0.f; lacc[r] = 0.f; }
  float mrun = -1e30f;

  const int krow_in_grp = lane >> 3;
  const int kchunk = (lane & 7) ^ krow_in_grp;
  const short* ksrc0 = kp + base + (size_t)(wid * 16 + krow_in_grp) * CDIM + kchunk * 8;
  const int vd0 = wid * 16;
  const short* vsrc0 = vp + base + (size_t)lane * CDIM + vd0;

  const float SC2 = 0.18033688011112042f;  // log2(e)/sqrt(64)
  const float THR2 = 11.54f;               // 8*log2(e)
  const int NT = LQ / 64;

  bf16x8 vv0, vv1;
  gl_lds16(ksrc0, &Kbuf[0][(wid * 16) * 64]);
  gl_lds16(ksrc0 + (size_t)8 * CDIM, &Kbuf[0][(wid * 16 + 8) * 64]);
  vv0 = *(const bf16x8*)(vsrc0);
  vv1 = *(const bf16x8*)(vsrc0 + 8);

  for (int kt = 0; kt < NT; ++kt) {
    const int cur = kt & 1;
    asm volatile("s_waitcnt vmcnt(0)" ::: "memory");
#pragma unroll
    for (int j = 0; j < 8; ++j) Vbuf[cur][swz(vd0 + j, lane)] = vv0[j];
#pragma unroll
    for (int j = 0; j < 8; ++j) Vbuf[cur][swz(vd0 + 8 + j, lane)] = vv1[j];
    __syncthreads();

    if (kt + 1 < NT) {
      const short* ks = ksrc0 + (size_t)(kt + 1) * 64 * CDIM;
      gl_lds16(ks, &Kbuf[cur ^ 1][(wid * 16) * 64]);
      gl_lds16(ks + (size_t)8 * CDIM, &Kbuf[cur ^ 1][(wid * 16 + 8) * 64]);
      const short* vs = vsrc0 + (size_t)(kt + 1) * 64 * CDIM;
      vv0 = *(const bf16x8*)(vs);
      vv1 = *(const bf16x8*)(vs + 8);
    }
    __builtin_amdgcn_sched_barrier(0);

    const short* Klds = Kbuf[cur];
    const short* Vt = Vbuf[cur];
    f32x16 c0, c1;
#pragma unroll
    for (int r = 0; r < 16; ++r) { c0[r] = 0.f; c1[r] = 0.f; }
    __builtin_amdgcn_s_setprio(1);
#pragma unroll
    for (int ds = 0; ds < 4; ++ds) {
      bf16x8 ka = *(const bf16x8*)&Klds[swz(l31, ds * 16 + hi * 8)];
      bf16x8 kb = *(const bf16x8*)&Klds[swz(32 + l31, ds * 16 + hi * 8)];
      c0 = __builtin_amdgcn_mfma_f32_32x32x16_bf16(ka, qf[ds], c0, 0, 0, 0);
      c1 = __builtin_amdgcn_mfma_f32_32x32x16_bf16(kb, qf[ds], c1, 0, 0, 0);
    }
    __builtin_amdgcn_s_setprio(0);

    // ---- max reduce (v_max3-friendly triples), exp2-domain defer-max ----
    float m = fmaxf(c0[0], c0[1]);
#pragma unroll
    for (int r = 2; r < 16; r += 2) m = fmaxf(fmaxf(m, c0[r]), c0[r + 1]);
#pragma unroll
    for (int r = 0; r < 16; r += 2) m = fmaxf(fmaxf(m, c1[r]), c1[r + 1]);
    m = fmaxf(m, __shfl_xor(m, 32, 64));
    float mx2 = m * SC2;
    if (__any(mx2 > mrun + THR2)) {
      float mn = fmaxf(mrun, mx2);
      float cr = exp2f(mrun - mn);
      mrun = mn;
      lacc[0] *= cr;
#pragma unroll
      for (int r = 0; r < 16; ++r) { o0[r] *= cr; o1[r] *= cr; }
    }
    float pr0[16], pr1[16];
#pragma unroll
    for (int r = 0; r < 16; ++r) {
      pr0[r] = exp2f(fmaf(c0[r], SC2, -mrun));
      pr1[r] = exp2f(fmaf(c1[r], SC2, -mrun));
    }

    bf16x8 pa0 = mkfrag(pr0);
    bf16x8 pa1 = mkfrag(pr0 + 8);
    bf16x8 pa2 = mkfrag(pr1);
    bf16x8 pa3 = mkfrag(pr1 + 8);

    // ---- O^T += V^T P^T ; row denominators via ones-MFMA (full kv sum, no shfl) ----
    __builtin_amdgcn_s_setprio(1);
#pragma unroll
    for (int ks = 0; ks < 4; ++ks) {
      bf16x8 pa = ks == 0 ? pa0 : ks == 1 ? pa1 : ks == 2 ? pa2 : pa3;
      bf16x8 v0 = *(const bf16x8*)&Vt[swz(l31, ks * 16 + hi * 8)];
      bf16x8 v1 = *(const bf16x8*)&Vt[swz(32 + l31, ks * 16 + hi * 8)];
      o0 = __builtin_amdgcn_mfma_f32_32x32x16_bf16(v0, pa, o0, 0, 0, 0);
      o1 = __builtin_amdgcn_mfma_f32_32x32x16_bf16(v1, pa, o1, 0, 0, 0);
      lacc = __builtin_amdgcn_mfma_f32_32x32x16_bf16(ones, pa, lacc, 0, 0, 0);
    }
    __builtin_amdgcn_s_setprio(0);
  }

  // ---- finalize: lacc[0] = full row denominator (k-dim spans both halves) ----
  float inv = 1.0f / lacc[0];
  short* orow = qp + base + (size_t)(qw + l31) * CDIM;
#pragma unroll
  for (int rq = 0; rq < 4; ++rq) {
    u32x2 w;
    w[0] = cvt_pk_bf16(o0[rq * 4 + 0] * inv, o0[rq * 4 + 1] * inv);
    w[1] = cvt_pk_bf16(o0[rq * 4 + 2] * inv, o0[rq * 4 + 3] * inv);
    *(u32x2*)(orow + rq * 8 + hi * 4) = w;
    w[0] = cvt_pk_bf16(o1[rq * 4 + 0] * inv, o1[rq * 4 + 1] * inv);
    w[1] = cvt_pk_bf16(o1[rq * 4 + 2] * inv, o1[rq * 4 + 3] * inv);
    *(u32x2*)(orow + 32 + rq * 8 + hi * 4) = w;
  }
}

extern "C" void kernel_launch(void* const* d_in, const int* in_sizes, int n_in,
                              void* d_out, int out_size, void* d_ws, size_t ws_size,
                              hipStream_t stream) {
  const float* q  = (const float*)d_in[0];
  const float* k  = (const float*)d_in[1];
  const float* v  = (const float*)d_in[2];
  const float* Wq = (const float*)d_in[3];
  const float* Wk = (const float*)d_in[4];
  const float* Wv = (const float*)d_in[5];
  const float* Wo = (const float*)d_in[6];
  float* out = (float*)d_out;

  // ws layout (shorts): [wbf 4M][vb 4M][qp 4M][kp 4M][vp 4M] = 40 MB
  short* wbf = (short*)d_ws;
  short* vb  = wbf + (size_t)4 * WELEM;
  short* qp  = vb + (size_t)TELEM;
  short* kp  = qp + (size_t)TELEM;
  short* vp  = kp + (size_t)TELEM;
  // qb/kb live in d_out as scratch (16 MB, exactly 2 bf16 tensors);
  // out_kernel fully overwrites d_out afterwards -> deterministic.
  short* qb = (short*)d_out;
  short* kb = qb + (size_t)TELEM;

  convall_kernel<<<2048, 256, 0, stream>>>(Wq, Wk, Wv, Wo, q, k, v, wbf, qb, kb, vb);
  proj_kernel<<<dim3(32, 24), 256, 0, stream>>>(qb, kb, vb, wbf, qp, kp, vp);
  attn_kernel<<<dim3(32, 16), 256, 0, stream>>>(kp, vp, qp);
  out_kernel<<<dim3(32, 16), 256, 0, stream>>>(qp, wbf + (size_t)3 * WELEM, out);
}